// Round 14
// baseline (204.116 us; speedup 1.0000x reference)
//
#include <hip/hip_runtime.h>
#include <hip/hip_cooperative_groups.h>

namespace cg = cooperative_groups;

#define LRELU_ALPHA 0.2f

typedef __bf16 bf16x8 __attribute__((ext_vector_type(8)));
typedef unsigned short u16;
typedef unsigned short u16x8 __attribute__((ext_vector_type(8)));
typedef float f32x4 __attribute__((ext_vector_type(4)));
typedef int int4v __attribute__((ext_vector_type(4)));
typedef unsigned int u32;
typedef unsigned long long u64;

__device__ __forceinline__ u16 f2bf(float f) {
  unsigned int u = __float_as_uint(f);
  u += 0x7fffu + ((u >> 16) & 1u);   // RNE
  return (u16)(u >> 16);
}

// ---------------- kernel 1: WbT[o][i] = bf16(W[i][o]) ----------------
__global__ __launch_bounds__(256) void wcast(const float* __restrict__ W,
                                             u16* __restrict__ WbT) {
  int idx = blockIdx.x * 256 + threadIdx.x;            // 65536
  WbT[idx] = f2bf(W[(idx & 255) * 256 + (idx >> 8)]);
}

// ---------------- kernel 2: fully fused cooperative GAT ----------------
// grid 256 (1/CU), 1024 thr / 16 waves, cooperative launch.
// Phase A: all 16 waves ballot-pack own 64 adj rows -> LDS Mk (no global
//          mask buffer); waves 0-3 also run gemm1 (R12-proven) writing
//          HhTt (tiled), sbuf, dbuf.   grid.sync().
// Phase B: R12/R13-proven K-loop: e-gen once into 4-buf At, one raw
//          s_barrier+lgkmcnt(0)/step, B free-floats from L2 (depth-1
//          reg prefetch), interleaved-bit mask extraction (R13 formulas).
__global__ __launch_bounds__(1024, 4) void fused(const int* __restrict__ adj,
                                                 const float* __restrict__ h,
                                                 const u16* __restrict__ WbT,
                                                 const float* __restrict__ a,
                                                 u16* __restrict__ HhTt,
                                                 float* __restrict__ sbuf,
                                                 float* __restrict__ dbuf,
                                                 float* __restrict__ out) {
  __shared__ __align__(16) u32 Mk[64 * 131];   // 33.5 KB mask panel (pad 131)
  __shared__ __align__(16) u16 At[4][2560];    // 20 KB: [buf][row64][k32+pad8]
  __shared__ float rs_lds[64];

  cg::grid_group grid = cg::this_grid();

  const int tid = threadIdx.x, bid = blockIdx.x;
  const int xcd = bid & 7;
  const int t = (xcd << 5) | (bid >> 3);       // 0..255 bijective
  const int b = t >> 6;                        // batch -> 2 XCDs
  const int rowbase = (t & 63) << 6;
  const size_t growbase = (size_t)b * 4096 + rowbase;

  const int l = tid & 63, w = tid >> 6;        // w 0..15

  // ======== PHASE A1: pack own 64 rows into LDS Mk via ballot ========
  // row r, chunk ch: ballots b0..b3 of int4 elems; bit layout (R13-proven):
  // col c -> word ch*8 + (c&3)*2 + (((c>>2)&63)>>5), bit (c>>2)&31.
#pragma unroll
  for (int q = 0; q < 4; ++q) {
    const int r = w * 4 + q;
    const int* arow = adj + (growbase + r) * 4096;
    for (int ch = 0; ch < 16; ++ch) {
      int4v v = *(const int4v*)(arow + ch * 256 + l * 4);
      u64 b0 = __ballot(v.x != 0);
      u64 b1 = __ballot(v.y != 0);
      u64 b2 = __ballot(v.z != 0);
      u64 b3 = __ballot(v.w != 0);
      if (l == 0) {
        const int base = r * 131 + ch * 8;
        Mk[base + 0] = (u32)b0; Mk[base + 1] = (u32)(b0 >> 32);
        Mk[base + 2] = (u32)b1; Mk[base + 3] = (u32)(b1 >> 32);
        Mk[base + 4] = (u32)b2; Mk[base + 5] = (u32)(b2 >> 32);
        Mk[base + 6] = (u32)b3; Mk[base + 7] = (u32)(b3 >> 32);
      }
    }
  }

  // ======== PHASE A2: gemm1 on waves 0-3 (R12-proven body) ========
  if (tid < 256) {
    const int w4 = tid >> 6;
    const int lr4 = l & 15;
    const int lk = (l >> 4) << 3;
    const size_t rowA = growbase + 16 * w4 + lr4;
    const float* hrow = h + rowA * 256 + lk;

    f32x4 acc[16];
#pragma unroll
    for (int n = 0; n < 16; ++n) acc[n] = (f32x4){0.f, 0.f, 0.f, 0.f};

    for (int k0 = 0; k0 < 256; k0 += 32) {
      f32x4 a0 = *(const f32x4*)(hrow + k0);
      f32x4 a1 = *(const f32x4*)(hrow + k0 + 4);
      u16x8 au;
      au[0] = f2bf(a0[0]); au[1] = f2bf(a0[1]); au[2] = f2bf(a0[2]); au[3] = f2bf(a0[3]);
      au[4] = f2bf(a1[0]); au[5] = f2bf(a1[1]); au[6] = f2bf(a1[2]); au[7] = f2bf(a1[3]);
      bf16x8 af = __builtin_bit_cast(bf16x8, au);
#pragma unroll
      for (int n = 0; n < 16; ++n) {
        int4v bv = *(const int4v*)(WbT + (size_t)(16 * n + lr4) * 256 + k0 + lk);
        bf16x8 bf = __builtin_bit_cast(bf16x8, bv);
        acc[n] = __builtin_amdgcn_mfma_f32_16x16x32_bf16(af, bf, acc[n], 0, 0, 0);
      }
    }

    float sp[4] = {0.f, 0.f, 0.f, 0.f}, dp[4] = {0.f, 0.f, 0.f, 0.f};
#pragma unroll
    for (int n = 0; n < 16; ++n) {
      int col = 16 * n + lr4;
      float as = a[col];
      float ad = a[256 + col];
#pragma unroll
      for (int rr = 0; rr < 4; ++rr) {
        size_t row = growbase + 16 * w4 + ((l >> 4) << 2) + rr;
        int bb = (int)(row >> 12), kk = (int)(row & 4095);
        float v = acc[n][rr];
        size_t addr = (size_t)bb * 1048576 + (size_t)(kk >> 5) * 8192 +
                      (col >> 4) * 512 + ((kk >> 3) & 3) * 128 + (col & 15) * 8 +
                      (kk & 7);
        HhTt[addr] = f2bf(v);
        sp[rr] += v * as;
        dp[rr] += v * ad;
      }
    }
#pragma unroll
    for (int rr = 0; rr < 4; ++rr) {
#pragma unroll
      for (int off = 1; off < 16; off <<= 1) {
        sp[rr] += __shfl_xor(sp[rr], off);
        dp[rr] += __shfl_xor(dp[rr], off);
      }
    }
    if ((l & 15) == 0) {
#pragma unroll
      for (int rr = 0; rr < 4; ++rr) {
        size_t row = growbase + 16 * w4 + ((l >> 4) << 2) + rr;
        sbuf[row] = sp[rr];
        dbuf[row] = dp[rr];
      }
    }
  }

  grid.sync();   // HhTt / sbuf / dbuf complete chip-wide; Mk in own LDS

  // ======== PHASE B: K-loop (R12/R13-proven, byte-identical) ========
  const int lr = l & 15, lkg = l >> 4;
  const int r = tid >> 4, kp = tid & 15;       // e-gen: row r, k-pair kp

  const float s_r = sbuf[growbase + r];
  const float* dtp = dbuf + (size_t)b * 4096 + kp * 2;
  const int mkr = r * 131;

  float racc = 0.f;

#define EGEN(BUF, STE)                                                        \
  {                                                                           \
    const int wb_ = ((STE) >> 3) * 8 + (kp & 1) * 4 + (((STE) & 7) >> 2);     \
    const int bp_ = ((STE) & 3) * 8 + (kp >> 1);                              \
    u32 w0_ = Mk[mkr + wb_];                                                  \
    u32 w1_ = Mk[mkr + wb_ + 2];                                              \
    float2 dv = *(const float2*)(dtp + (STE) * 32);                           \
    float lg0 = s_r + dv.x;                                                   \
    float t0 = fmaxf(lg0, LRELU_ALPHA * lg0);                                 \
    float e0 = ((w0_ >> bp_) & 1u) ? __expf(-t0) : 0.f;                       \
    float lg1 = s_r + dv.y;                                                   \
    float t1 = fmaxf(lg1, LRELU_ALPHA * lg1);                                 \
    float e1 = ((w1_ >> bp_) & 1u) ? __expf(-t1) : 0.f;                       \
    racc += e0 + e1;                                                          \
    u32 pk;                                                                   \
    asm("v_cvt_pk_bf16_f32 %0, %1, %2" : "=v"(pk) : "v"(e0), "v"(e1));        \
    *(u32*)&At[BUF][r * 40 + kp * 2] = pk;                                    \
  }

  EGEN(0, 0)

  const char* bbase = (const char*)HhTt + (size_t)b * 2097152 + w * 1024 + l * 16;
  int4v Bcur = *(const int4v*)(bbase);

  f32x4 acc[4];
#pragma unroll
  for (int n = 0; n < 4; ++n) acc[n] = (f32x4){0.f, 0.f, 0.f, 0.f};

  for (int st = 0; st < 128; ++st) {
    if (st < 127) EGEN((st + 1) & 3, st + 1)
    const int pst = (st < 127) ? st + 1 : st;
    int4v Bnext = *(const int4v*)(bbase + (size_t)pst * 16384);

    asm volatile("s_waitcnt lgkmcnt(0)" ::: "memory");
    __builtin_amdgcn_s_barrier();
    __builtin_amdgcn_sched_barrier(0);

    const u16* atb = &At[st & 3][0];
    int4v a0 = *(const int4v*)(atb + (0 * 16 + lr) * 40 + lkg * 8);
    int4v a1 = *(const int4v*)(atb + (1 * 16 + lr) * 40 + lkg * 8);
    int4v a2 = *(const int4v*)(atb + (2 * 16 + lr) * 40 + lkg * 8);
    int4v a3 = *(const int4v*)(atb + (3 * 16 + lr) * 40 + lkg * 8);
    bf16x8 bfv = __builtin_bit_cast(bf16x8, Bcur);
    __builtin_amdgcn_s_setprio(1);
    acc[0] = __builtin_amdgcn_mfma_f32_16x16x32_bf16(
        __builtin_bit_cast(bf16x8, a0), bfv, acc[0], 0, 0, 0);
    acc[1] = __builtin_amdgcn_mfma_f32_16x16x32_bf16(
        __builtin_bit_cast(bf16x8, a1), bfv, acc[1], 0, 0, 0);
    acc[2] = __builtin_amdgcn_mfma_f32_16x16x32_bf16(
        __builtin_bit_cast(bf16x8, a2), bfv, acc[2], 0, 0, 0);
    acc[3] = __builtin_amdgcn_mfma_f32_16x16x32_bf16(
        __builtin_bit_cast(bf16x8, a3), bfv, acc[3], 0, 0, 0);
    __builtin_amdgcn_s_setprio(0);
    Bcur = Bnext;
  }
#undef EGEN

  // ---- rowsum: 16 kp-partials per row in one 16-lane group ----
  racc += __shfl_xor(racc, 1);
  racc += __shfl_xor(racc, 2);
  racc += __shfl_xor(racc, 4);
  racc += __shfl_xor(racc, 8);
  if (kp == 0) rs_lds[r] = (racc == 0.f) ? 1.f : racc;
  __syncthreads();

  // ---- epilogue: divide + elu + store (C/D: col=l&15, row=(l>>4)*4+reg) ----
#pragma unroll
  for (int rt = 0; rt < 4; ++rt) {
#pragma unroll
    for (int reg = 0; reg < 4; ++reg) {
      int rloc = rt * 16 + lkg * 4 + reg;
      float rsv = rs_lds[rloc];
      float v = acc[rt][reg] / rsv;
      out[(growbase + rloc) * 256 + w * 16 + lr] =
          v > 0.f ? v : (__expf(v) - 1.f);
    }
  }
}

extern "C" void kernel_launch(void* const* d_in, const int* in_sizes, int n_in,
                              void* d_out, int out_size, void* d_ws, size_t ws_size,
                              hipStream_t stream) {
  const int* adj = (const int*)d_in[1];
  const float* h = (const float*)d_in[0];
  const float* W = (const float*)d_in[2];
  const float* a = (const float*)d_in[3];
  float* out = (float*)d_out;

  u16* WbT  = (u16*)d_ws;                                  // 128 KB
  u16* HhTt = (u16*)((char*)d_ws + 131072);                // 8 MB
  float* sb = (float*)((char*)d_ws + 131072 + 8388608);    // 64 KB
  float* db = sb + 16384;                                  // 64 KB

  hipLaunchKernelGGL(wcast, dim3(256), dim3(256), 0, stream, W, WbT);

  void* args[] = {(void*)&adj, (void*)&h, (void*)&WbT, (void*)&a,
                  (void*)&HhTt, (void*)&sb, (void*)&db, (void*)&out};
  hipLaunchCooperativeKernel((void*)fused, dim3(256), dim3(1024), args, 0,
                             stream);
}